// Round 1
// baseline (468.813 us; speedup 1.0000x reference)
//
#include <hip/hip_runtime.h>
#include <math.h>

#define GROUPS_PER_BLOCK 16
#define THREADS 256

// One 16-lane group per batch element. Lane t (0..15) owns output capsule
// m = min(t,11); lanes 12..15 are padding that carry -inf logits through the
// softmax shuffles (they execute everything, never store).
__global__ __launch_bounds__(THREADS, 2) void capsnet_kernel(
    const float* __restrict__ x,      // [B,210]
    const float* __restrict__ W_pc,   // [7,8,30]
    const float* __restrict__ b_pc,   // [7,8]
    const float* __restrict__ W,      // [7,12,8,16]
    const int*  __restrict__ p_niter,
    float* __restrict__ out,          // [B,12]
    int B)
{
    __shared__ float xs[GROUPS_PER_BLOCK][210];  // staged input rows
    __shared__ float us[GROUPS_PER_BLOCK][56];   // primary capsules (squashed)

    const int tid = threadIdx.x;
    const int g   = tid >> 4;      // group within block
    const int t   = tid & 15;      // lane within group
    int b = blockIdx.x * GROUPS_PER_BLOCK + g;
    const bool valid_b = (b < B);
    if (!valid_b) b = B - 1;       // clamp: compute redundantly, skip store
    const int niter = *p_niter;

    // ---- stage x[b] into LDS (float2 vectorized, 105 float2 per row) ----
    {
        const float2* xrow = (const float2*)(x + (size_t)b * 210);
        float2* xdst = (float2*)&xs[g][0];
        #pragma unroll
        for (int i = 0; i < 7; ++i) {
            int idx = t + 16 * i;
            if (idx < 105) xdst[idx] = xrow[idx];
        }
    }
    __syncthreads();

    // ---- primary capsules: pc[n][o] = x_group[n]·W_pc[n][o] + b_pc[n][o] ----
    #pragma unroll
    for (int i = 0; i < 4; ++i) {
        int idx = t + 16 * i;                 // idx = n*8 + o, 56 outputs
        if (idx < 56) {
            int n = idx >> 3;
            const float2* wrow2 = (const float2*)(W_pc + idx * 30);
            const float2* xr2   = (const float2*)&xs[g][n * 30];
            float acc = b_pc[idx];
            #pragma unroll
            for (int gg = 0; gg < 15; ++gg) {
                float2 wv = wrow2[gg];
                float2 xv = xr2[gg];
                acc += xv.x * wv.x;
                acc += xv.y * wv.y;
            }
            us[g][idx] = acc;
        }
    }
    __syncthreads();

    // ---- squash primary capsules per n (lanes 0..6, one n each) ----
    if (t < 7) {
        float vals[8];
        float s2 = 0.f;
        #pragma unroll
        for (int o = 0; o < 8; ++o) {
            vals[o] = us[g][t * 8 + o];
            s2 += vals[o] * vals[o];
        }
        float nrm = sqrtf(s2);
        float f = nrm / ((1.f + nrm * nrm) * (nrm + 1e-8f));
        #pragma unroll
        for (int o = 0; o < 8; ++o) us[g][t * 8 + o] = vals[o] * f;
    }
    __syncthreads();

    // ---- u_hat[n][m][k] = sum_j u[n][j] * W[n][m][j][k], kept in registers ----
    const int m = (t < 12) ? t : 11;   // clamp keeps W reads in-bounds
    float uh[7][16];
    #pragma unroll
    for (int n = 0; n < 7; ++n) {
        float uu[8];
        {
            float4 a = *(const float4*)&us[g][n * 8];
            float4 c4 = *(const float4*)&us[g][n * 8 + 4];
            uu[0] = a.x; uu[1] = a.y; uu[2] = a.z; uu[3] = a.w;
            uu[4] = c4.x; uu[5] = c4.y; uu[6] = c4.z; uu[7] = c4.w;
        }
        #pragma unroll
        for (int k = 0; k < 16; ++k) uh[n][k] = 0.f;
        const float* Wn = W + (size_t)(n * 12 + m) * 128;
        #pragma unroll
        for (int j = 0; j < 8; ++j) {
            float uj = uu[j];
            const float4* wr = (const float4*)(Wn + j * 16);
            float w[16];
            *(float4*)&w[0]  = wr[0];
            *(float4*)&w[4]  = wr[1];
            *(float4*)&w[8]  = wr[2];
            *(float4*)&w[12] = wr[3];
            #pragma unroll
            for (int k = 0; k < 16; ++k) uh[n][k] += uj * w[k];
        }
    }

    // ---- dynamic routing ----
    const bool active = (t < 12);
    float blog[7];
    #pragma unroll
    for (int n = 0; n < 7; ++n) blog[n] = 0.f;
    float vnorm = 0.f;
    const float NEG_INF = -__builtin_inff();

    for (int it = 0; it < niter; ++it) {
        // softmax over m (cross-lane within the 16-lane group)
        float c[7];
        #pragma unroll
        for (int n = 0; n < 7; ++n) {
            float bb = active ? blog[n] : NEG_INF;
            float mx = bb;
            #pragma unroll
            for (int d = 1; d < 16; d <<= 1)
                mx = fmaxf(mx, __shfl_xor(mx, d, 16));
            float e = expf(bb - mx);
            float sm = e;
            #pragma unroll
            for (int d = 1; d < 16; d <<= 1)
                sm += __shfl_xor(sm, d, 16);
            c[n] = e / sm;
        }
        // s[k] = sum_n c[n] * uh[n][k]   (lane-local)
        float s[16];
        #pragma unroll
        for (int k = 0; k < 16; ++k) s[k] = 0.f;
        #pragma unroll
        for (int n = 0; n < 7; ++n) {
            float cn = c[n];
            #pragma unroll
            for (int k = 0; k < 16; ++k) s[k] += cn * uh[n][k];
        }
        // squash
        float s2 = 0.f;
        #pragma unroll
        for (int k = 0; k < 16; ++k) s2 += s[k] * s[k];
        float nrm = sqrtf(s2);
        float f = nrm / ((1.f + nrm * nrm) * (nrm + 1e-8f));
        if (it == niter - 1) {
            vnorm = f * nrm;           // ||v|| = f * ||s||
        } else {
            #pragma unroll
            for (int k = 0; k < 16; ++k) s[k] *= f;   // s becomes v
            #pragma unroll
            for (int n = 0; n < 7; ++n) {
                float d = 0.f;
                #pragma unroll
                for (int k = 0; k < 16; ++k) d += uh[n][k] * s[k];
                blog[n] += d;          // b[n][m] += u_hat[n][m]·v[m]
            }
        }
    }

    if (active && valid_b) out[(size_t)b * 12 + t] = vnorm;
}

extern "C" void kernel_launch(void* const* d_in, const int* in_sizes, int n_in,
                              void* d_out, int out_size, void* d_ws, size_t ws_size,
                              hipStream_t stream) {
    const float* x    = (const float*)d_in[0];
    const float* W_pc = (const float*)d_in[1];
    const float* b_pc = (const float*)d_in[2];
    const float* W    = (const float*)d_in[3];
    const int* niter  = (const int*)d_in[4];
    float* out = (float*)d_out;

    int B = in_sizes[0] / 210;
    int blocks = (B + GROUPS_PER_BLOCK - 1) / GROUPS_PER_BLOCK;
    capsnet_kernel<<<blocks, THREADS, 0, stream>>>(x, W_pc, b_pc, W, niter, out, B);
}